// Round 7
// baseline (125.414 us; speedup 1.0000x reference)
//
#include <hip/hip_runtime.h>

// ---------------------------------------------------------------------------
// CausalSelfAttention: fake-quant-i4 weights -> QKV gemm -> RMSNorm+RoPE+gain
// -> GQA causal flash attention -> out proj.  bf16 MFMA (16x16x32), fp32 acc.
// B=2 S=2048 H=16 KVH=4 D=64 DIM=1024.  2-phase double-buffered staging.
// ---------------------------------------------------------------------------

typedef __bf16 bf16x8 __attribute__((ext_vector_type(8)));
typedef __bf16 bf16x4 __attribute__((ext_vector_type(4)));
typedef float  f32x4  __attribute__((ext_vector_type(4)));

__device__ __forceinline__ unsigned short f2bf(float f) {
  __bf16 h = (__bf16)f;                     // HW RNE cvt
  return __builtin_bit_cast(unsigned short, h);
}

// ---------------- fake_quant_i4 rows -> bf16 -------------------------------
__global__ void quant_rows(const float* __restrict__ src,
                           unsigned short* __restrict__ dst, int ncols) {
  int row = blockIdx.x;
  const float* s = src + (size_t)row * ncols;
  unsigned short* d = dst + (size_t)row * ncols;
  int t = threadIdx.x;
  float v[4]; float mx = 0.f;
#pragma unroll
  for (int i = 0; i < 4; i++) { v[i] = s[t + 256 * i]; mx = fmaxf(mx, fabsf(v[i])); }
#pragma unroll
  for (int m = 1; m < 64; m <<= 1) mx = fmaxf(mx, __shfl_xor(mx, m));
  __shared__ float smx[4];
  if ((t & 63) == 0) smx[t >> 6] = mx;
  __syncthreads();
  mx = fmaxf(fmaxf(smx[0], smx[1]), fmaxf(smx[2], smx[3]));
  mx = fmaxf(mx, 1e-8f);
  float scale = mx / 7.0f;                  // exact div to match jnp
#pragma unroll
  for (int i = 0; i < 4; i++) {
    float q = rintf(v[i] / scale);          // RNE == jnp.round
    q = fminf(fmaxf(q, -7.0f), 7.0f);
    d[t + 256 * i] = f2bf(q * scale);
  }
}

// ---------------- f32 -> bf16 ----------------------------------------------
__global__ void cvt_bf16(const float* __restrict__ src,
                         unsigned short* __restrict__ dst, int n) {
  int i = (blockIdx.x * 256 + threadIdx.x) * 4;
  if (i >= n) return;
  float4 f = *(const float4*)(src + i);
  ushort4 o;
  o.x = f2bf(f.x); o.y = f2bf(f.y); o.z = f2bf(f.z); o.w = f2bf(f.w);
  *(ushort4*)(dst + i) = o;
}

// ---------------- GEMM: C[M,N] = A[M,K] * B[N,K]^T  (bf16 in, f32 out) -----
// 128x128 tile, BK=64, double-buffered LDS (2-phase), both-sides XOR swizzle.
#define GLDS(g, l)                                                            \
  __builtin_amdgcn_global_load_lds((const __attribute__((address_space(1))) void*)(g), \
                                   (__attribute__((address_space(3))) void*)(l), 16, 0, 0)

__global__ __launch_bounds__(256, 2) void gemm_bt(
    const unsigned short* __restrict__ A, const unsigned short* __restrict__ Bw,
    float* __restrict__ C, int N, int K, int nbn) {
  int bm = blockIdx.x / nbn, bn = blockIdx.x % nbn;
  int tid = threadIdx.x, w = tid >> 6, lane = tid & 63;
  int l15 = lane & 15, lh = lane >> 4;
  __shared__ __align__(16) unsigned short ldsA[2][128 * 64];
  __shared__ __align__(16) unsigned short ldsB[2][128 * 64];
  int wr = w >> 1, wc = w & 1;
  f32x4 zero = {0.f, 0.f, 0.f, 0.f};
  f32x4 acc[4][4];
#pragma unroll
  for (int i = 0; i < 4; i++)
#pragma unroll
    for (int j = 0; j < 4; j++) acc[i][j] = zero;

  int srow = lane >> 3, schunk = (lane & 7) ^ (lane >> 3);
  const unsigned short* gA0 = A  + (size_t)(bm * 128 + srow) * K + schunk * 8;
  const unsigned short* gB0 = Bw + (size_t)(bn * 128 + srow) * K + schunk * 8;

  int nk = K >> 6;
  // prologue: stage kt=0 into buf0
#pragma unroll
  for (int it = 0; it < 4; it++) {
    int seg = w * 4 + it;
    GLDS(gA0 + (size_t)(seg * 8) * K, (unsigned short*)ldsA[0] + seg * 512);
    GLDS(gB0 + (size_t)(seg * 8) * K, (unsigned short*)ldsB[0] + seg * 512);
  }
  __syncthreads();
  int cur = 0;
  for (int kt = 0; kt < nk; kt++) {
    if (kt + 1 < nk) {
      int k0 = (kt + 1) * 64;
#pragma unroll
      for (int it = 0; it < 4; it++) {
        int seg = w * 4 + it;
        GLDS(gA0 + (size_t)(seg * 8) * K + k0, (unsigned short*)ldsA[cur ^ 1] + seg * 512);
        GLDS(gB0 + (size_t)(seg * 8) * K + k0, (unsigned short*)ldsB[cur ^ 1] + seg * 512);
      }
    }
    const unsigned short* cA = ldsA[cur];
    const unsigned short* cB = ldsB[cur];
#pragma unroll
    for (int ks = 0; ks < 2; ks++) {
      bf16x8 af[4], bfr[4];
#pragma unroll
      for (int fm = 0; fm < 4; fm++) {
        int row = wr * 64 + fm * 16 + l15;
        int slot = (ks * 4 + lh) ^ (row & 7);
        af[fm] = *(const bf16x8*)(cA + row * 64 + slot * 8);
      }
#pragma unroll
      for (int fn = 0; fn < 4; fn++) {
        int row = wc * 64 + fn * 16 + l15;
        int slot = (ks * 4 + lh) ^ (row & 7);
        bfr[fn] = *(const bf16x8*)(cB + row * 64 + slot * 8);
      }
#pragma unroll
      for (int fm = 0; fm < 4; fm++)
#pragma unroll
        for (int fn = 0; fn < 4; fn++)
          acc[fm][fn] = __builtin_amdgcn_mfma_f32_16x16x32_bf16(af[fm], bfr[fn], acc[fm][fn], 0, 0, 0);
    }
    __syncthreads();
    cur ^= 1;
  }
#pragma unroll
  for (int fm = 0; fm < 4; fm++) {
    int r0 = bm * 128 + wr * 64 + fm * 16 + lh * 4;
#pragma unroll
    for (int fn = 0; fn < 4; fn++) {
      int c = bn * 128 + wc * 64 + fn * 16 + l15;
#pragma unroll
      for (int reg = 0; reg < 4; reg++)
        C[(size_t)(r0 + reg) * N + c] = acc[fm][fn][reg];
    }
  }
}

// ---------------- RMSNorm + RoPE + gain for Q,K ----------------------------
__global__ void postproc_qk(const float* __restrict__ qkv,
                            const float* __restrict__ gain,
                            unsigned short* __restrict__ qb,
                            unsigned short* __restrict__ kb) {
  int task = blockIdx.x * 4 + (threadIdx.x >> 6);
  int lane = threadIdx.x & 63;
  int token = task / 20, hh = task % 20;
  int b = token >> 11, s = token & 2047;
  bool isq = hh < 16;
  const float* src = qkv + (size_t)token * 1536 + (isq ? hh * 64 : 1024 + (hh - 16) * 64);
  float x = src[lane];
  float ss = x * x;
#pragma unroll
  for (int m = 1; m < 64; m <<= 1) ss += __shfl_xor(ss, m);
  x *= rsqrtf(ss * (1.0f / 64.0f) + 1.1920929e-7f);
  int i = lane & 31;
  float invf = __expf(-0.28782313662425572f * (float)i);  // ln(10000)/32
  float ang = (float)s * invf;
  float c, sn;
  __sincosf(ang, &sn, &c);
  float x1 = __shfl(x, i);
  float x2 = __shfl(x, i + 32);
  float out = (lane < 32) ? (x1 * c + x2 * sn) : (x2 * c - x1 * sn);
  if (isq) {
    out *= gain[hh];
    qb[((size_t)(b * 16 + hh) * 2048 + s) * 64 + lane] = f2bf(out);
  } else {
    kb[((size_t)(b * 4 + (hh - 16)) * 2048 + s) * 64 + lane] = f2bf(out);
  }
}

// ---------------- V transpose + kv-permute (per-64 group) ------------------
// Vp[d][g*64 + p] = V[g*64 + c64(p)][d],  c64(p) = ((p&3)<<4)|(p>>2).
// The SAME within-64 permutation is applied to P columns in attn (store at
// position l15*4+fn for value col fn*16+l15), so P.V is invariant.
__global__ void v_transpose(const float* __restrict__ qkv,
                            unsigned short* __restrict__ vt) {
  int bid = blockIdx.x;
  int st = bid & 15, kvh = (bid >> 4) & 3, b = bid >> 6;
  __shared__ unsigned short tile[128][72];
  int t = threadIdx.x;
  int sl = t >> 1, d0 = (t & 1) * 32;
  const float* src = qkv + (size_t)(b * 2048 + st * 128 + sl) * 1536 + 1280 + kvh * 64 + d0;
#pragma unroll
  for (int j = 0; j < 32; j += 4) {
    float4 f = *(const float4*)(src + j);
    unsigned int lo = f2bf(f.x) | ((unsigned int)f2bf(f.y) << 16);
    unsigned int hi = f2bf(f.z) | ((unsigned int)f2bf(f.w) << 16);
    *(unsigned int*)&tile[sl][d0 + j]     = lo;
    *(unsigned int*)&tile[sl][d0 + j + 2] = hi;
  }
  __syncthreads();
  int d = t >> 2, pc = (t & 3) * 32;
  unsigned short* dst = vt + ((size_t)(b * 4 + kvh) * 64 + d) * 2048 + st * 128 + pc;
#pragma unroll
  for (int jo = 0; jo < 32; jo += 4) {
    ushort4 a;
#pragma unroll
    for (int j = 0; j < 4; j++) {
      int p = pc + jo + j;
      int p64 = p & 63;
      int c = (p & ~63) | ((p64 & 3) << 4) | (p64 >> 2);
      ((unsigned short*)&a)[j] = tile[c][d];
    }
    *(ushort4*)(dst + jo) = a;
  }
}

// ---------------- causal flash attention (4-wave, dbuf KV=64) --------------
// block = (b, h, q-block of 128); 4 waves x 32 q-rows.  KV tile = 64, K and
// V double-buffered in LDS (global_load_lds, both-sides XOR swizzle); single
// barrier per tile: stage(t+1) -> compute(t) -> syncthreads.
#define PSTR 72

template<bool MASK>
__device__ __forceinline__ void attn_tile(
    int kv0, int q0, int l15, int lh, float M2,
    const unsigned short* ldsK, const unsigned short* ldsV, unsigned short* pw,
    const bf16x8 (&qf)[2][2], float (&lsum)[2][4], f32x4 (&o)[2][4]) {
  const float K2 = 0.18033688011112042f;  // 0.125 * log2(e)
  f32x4 zero = {0.f, 0.f, 0.f, 0.f};
  f32x4 sc[2][4];
#pragma unroll
  for (int fm = 0; fm < 2; fm++)
#pragma unroll
    for (int fn = 0; fn < 4; fn++) sc[fm][fn] = zero;
  // --- QK^T (K from LDS) ---
#pragma unroll
  for (int ks = 0; ks < 2; ks++) {
    bf16x8 kf[4];
#pragma unroll
    for (int fn = 0; fn < 4; fn++) {
      int row = fn * 16 + l15;
      int slot = (ks * 4 + lh) ^ (row & 7);
      kf[fn] = *(const bf16x8*)(ldsK + row * 64 + slot * 8);
    }
#pragma unroll
    for (int fm = 0; fm < 2; fm++)
#pragma unroll
      for (int fn = 0; fn < 4; fn++)
        sc[fm][fn] = __builtin_amdgcn_mfma_f32_16x16x32_bf16(qf[fm][ks], kf[fn], sc[fm][fn], 0, 0, 0);
  }
  // --- softmax with STATIC max bound M2 (exp2 domain); plain sum ---
#pragma unroll
  for (int fm = 0; fm < 2; fm++)
#pragma unroll
    for (int r = 0; r < 4; r++) {
      bf16x4 pk;
      float ls = 0.f;
#pragma unroll
      for (int fn = 0; fn < 4; fn++) {
        float s = __builtin_fmaf(sc[fm][fn][r], K2, -M2);
        if (MASK) {
          int col = kv0 + fn * 16 + l15;
          int row = q0 + fm * 16 + lh * 4 + r;
          if (col > row) s = -1e30f;
        }
        float p = __builtin_amdgcn_exp2f(s);
        ls += p;
        pk[fn] = (__bf16)p;
      }
      // permuted store: value (fn,l15) -> position l15*4+fn  (one b64)
      *(bf16x4*)(pw + (fm * 16 + lh * 4 + r) * PSTR + l15 * 4) = pk;
      lsum[fm][r] += ls;
    }
  asm volatile("s_waitcnt lgkmcnt(0)" ::: "memory");
  __builtin_amdgcn_sched_barrier(0);
  // --- P.V (kv-permuted both sides), V from LDS ---
#pragma unroll
  for (int ks2 = 0; ks2 < 2; ks2++) {
    bf16x8 vf[4], pf[2];
#pragma unroll
    for (int fn = 0; fn < 4; fn++) {
      int row = fn * 16 + l15;
      int slot = (ks2 * 4 + lh) ^ (row & 7);
      vf[fn] = *(const bf16x8*)(ldsV + row * 64 + slot * 8);
    }
#pragma unroll
    for (int fm = 0; fm < 2; fm++)
      pf[fm] = *(const bf16x8*)(pw + (fm * 16 + l15) * PSTR + ks2 * 32 + lh * 8);
#pragma unroll
    for (int fm = 0; fm < 2; fm++)
#pragma unroll
      for (int fn = 0; fn < 4; fn++)
        o[fm][fn] = __builtin_amdgcn_mfma_f32_16x16x32_bf16(pf[fm], vf[fn], o[fm][fn], 0, 0, 0);
  }
}

__global__ __launch_bounds__(256, 3) void attn_fwd(
    const unsigned short* __restrict__ qbuf, const unsigned short* __restrict__ kb,
    const unsigned short* __restrict__ vtb, const float* __restrict__ gain,
    unsigned short* __restrict__ ob) {
  int bid = blockIdx.x;
  int g = bid >> 5;
  int qblk = (g < 8) ? (15 - g) : (g - 8);   // pair heavy+light per CU
  int bh = bid & 31;
  int b = bh >> 4, h = bh & 15;
  int tid = threadIdx.x;
  int w = tid >> 6, lane = tid & 63;
  int l15 = lane & 15, lh = lane >> 4;
  int q0 = qblk * 128 + w * 32;
  int kvh = h >> 2;
  const unsigned short* Q  = qbuf + (size_t)(b * 16 + h) * (2048 * 64);
  const unsigned short* Kg = kb   + (size_t)(b * 4 + kvh) * (2048 * 64);
  const unsigned short* Vg = vtb  + (size_t)(b * 4 + kvh) * (64 * 2048);

  __shared__ __align__(16) unsigned short ldsK[2][64 * 64];    // 16 KB
  __shared__ __align__(16) unsigned short ldsV[2][64 * 64];    // 16 KB
  __shared__ __align__(16) unsigned short plds[4][32 * PSTR];  // 18 KB
  unsigned short* pw = plds[w];

  float gn = gain[h];
  float M2 = __builtin_fmaf(fabsf(gn), 1.46f, 0.02f);  // static max bound

  bf16x8 qf[2][2];
#pragma unroll
  for (int fm = 0; fm < 2; fm++)
#pragma unroll
    for (int ks = 0; ks < 2; ks++)
      qf[fm][ks] = *(const bf16x8*)(Q + (q0 + fm * 16 + l15) * 64 + ks * 32 + lh * 8);

  f32x4 zero = {0.f, 0.f, 0.f, 0.f};
  f32x4 o[2][4];
  float lsum[2][4];
#pragma unroll
  for (int fm = 0; fm < 2; fm++)
#pragma unroll
    for (int r = 0; r < 4; r++) { lsum[fm][r] = 0.f; o[fm][r] = zero; }

  // staging lane geometry: 8 segs/operand (8 rows each), 2 per wave
  int srow = lane >> 3;                    // row within 8-row segment
  int schunk = (lane & 7) ^ (lane >> 3);   // pre-swizzled global chunk
  int full = q0 >> 6;                      // # fully-unmasked 64-kv tiles
  int nt = 2 * qblk + 2;

  // prologue: stage tile 0 into buf 0
#pragma unroll
  for (int it = 0; it < 2; it++) {
    int seg = w * 2 + it;
    GLDS(Kg + (size_t)(seg * 8 + srow) * 64 + schunk * 8,
         (unsigned short*)ldsK[0] + seg * 512);
    GLDS(Vg + (size_t)(seg * 8 + srow) * 2048 + schunk * 8,
         (unsigned short*)ldsV[0] + seg * 512);
  }
  __syncthreads();
  int cur = 0;
  for (int t = 0; t < nt; t++) {
    int kv0 = t * 64;
    if (t + 1 < nt) {
      int kn = kv0 + 64;
#pragma unroll
      for (int it = 0; it < 2; it++) {
        int seg = w * 2 + it;
        GLDS(Kg + (size_t)(kn + seg * 8 + srow) * 64 + schunk * 8,
             (unsigned short*)ldsK[cur ^ 1] + seg * 512);
        GLDS(Vg + (size_t)(seg * 8 + srow) * 2048 + kn + schunk * 8,
             (unsigned short*)ldsV[cur ^ 1] + seg * 512);
      }
    }
    if (t < full)
      attn_tile<false>(kv0, q0, l15, lh, M2, ldsK[cur], ldsV[cur], pw, qf, lsum, o);
    else if (kv0 <= q0 + 31)
      attn_tile<true>(kv0, q0, l15, lh, M2, ldsK[cur], ldsV[cur], pw, qf, lsum, o);
    __syncthreads();
    cur ^= 1;
  }

#pragma unroll
  for (int fm = 0; fm < 2; fm++)
#pragma unroll
    for (int r = 0; r < 4; r++) {
      float l = lsum[fm][r];
      l += __shfl_xor(l, 1);
      l += __shfl_xor(l, 2);
      l += __shfl_xor(l, 4);
      l += __shfl_xor(l, 8);
      float inv = 1.0f / l;
      int row = q0 + fm * 16 + lh * 4 + r;
#pragma unroll
      for (int fn = 0; fn < 4; fn++) {
        int c = fn * 16 + l15;
        ob[(size_t)(b * 2048 + row) * 1024 + h * 64 + c] = f2bf(o[fm][fn][r] * inv);
      }
    }
}

// ---------------------------------------------------------------------------
extern "C" void kernel_launch(void* const* d_in, const int* in_sizes, int n_in,
                              void* d_out, int out_size, void* d_ws, size_t ws_size,
                              hipStream_t stream) {
  const float* x    = (const float*)d_in[0];
  const float* w_q  = (const float*)d_in[1];
  const float* w_k  = (const float*)d_in[2];
  const float* w_v  = (const float*)d_in[3];
  const float* w_p  = (const float*)d_in[4];
  const float* gain = (const float*)d_in[5];
  float* out = (float*)d_out;

  char* ws = (char*)d_ws;
  unsigned short* x_bf  = (unsigned short*)ws;                   //  8 MB
  unsigned short* wqkv  = (unsigned short*)(ws + (8u << 20));    //  3 MB
  unsigned short* wp    = (unsigned short*)(ws + (11u << 20));   //  2 MB
  float*          qkv   = (float*)(ws + (13u << 20));            // 24 MB
  unsigned short* qbuf  = (unsigned short*)(ws + (37u << 20));   //  8 MB
  unsigned short* kbuf  = (unsigned short*)(ws + (45u << 20));   //  2 MB
  unsigned short* vtbuf = (unsigned short*)(ws + (47u << 20));   //  2 MB
  unsigned short* aout  = (unsigned short*)(ws + (49u << 20));   //  8 MB

  quant_rows<<<1024, 256, 0, stream>>>(w_q, wqkv, 1024);
  quant_rows<<<256, 256, 0, stream>>>(w_k, wqkv + 1024 * 1024, 1024);
  quant_rows<<<256, 256, 0, stream>>>(w_v, wqkv + 1280 * 1024, 1024);
  quant_rows<<<1024, 256, 0, stream>>>(w_p, wp, 1024);
  cvt_bf16<<<4096, 256, 0, stream>>>(x, x_bf, 4194304);
  gemm_bt<<<32 * 12, 256, 0, stream>>>(x_bf, wqkv, qkv, 1536, 1024, 12);
  postproc_qk<<<20480, 256, 0, stream>>>(qkv, gain, qbuf, kbuf);
  v_transpose<<<128, 256, 0, stream>>>(qkv, vtbuf);
  attn_fwd<<<512, 256, 0, stream>>>(qbuf, kbuf, vtbuf, gain, aout);
  gemm_bt<<<32 * 8, 256, 0, stream>>>(aout, wp, out, 1024, 1024, 8);
}

// Round 8
// 110.347 us; speedup vs baseline: 1.1365x; 1.1365x over previous
//
#include <hip/hip_runtime.h>

// ---------------------------------------------------------------------------
// CausalSelfAttention: fake-quant-i4 weights -> QKV gemm (fused RMSNorm+RoPE+
// gain epilogue) -> GQA causal flash attention -> out proj.
// bf16 MFMA (16x16x32), fp32 acc.  B=2 S=2048 H=16 KVH=4 D=64 DIM=1024.
// ---------------------------------------------------------------------------

typedef __bf16 bf16x8 __attribute__((ext_vector_type(8)));
typedef __bf16 bf16x4 __attribute__((ext_vector_type(4)));
typedef float  f32x4  __attribute__((ext_vector_type(4)));

__device__ __forceinline__ unsigned short f2bf(float f) {
  __bf16 h = (__bf16)f;                     // HW RNE cvt
  return __builtin_bit_cast(unsigned short, h);
}

// ---------------- fake_quant_i4 rows -> bf16 -------------------------------
__global__ void quant_rows(const float* __restrict__ src,
                           unsigned short* __restrict__ dst, int ncols) {
  int row = blockIdx.x;
  const float* s = src + (size_t)row * ncols;
  unsigned short* d = dst + (size_t)row * ncols;
  int t = threadIdx.x;
  float v[4]; float mx = 0.f;
#pragma unroll
  for (int i = 0; i < 4; i++) { v[i] = s[t + 256 * i]; mx = fmaxf(mx, fabsf(v[i])); }
#pragma unroll
  for (int m = 1; m < 64; m <<= 1) mx = fmaxf(mx, __shfl_xor(mx, m));
  __shared__ float smx[4];
  if ((t & 63) == 0) smx[t >> 6] = mx;
  __syncthreads();
  mx = fmaxf(fmaxf(smx[0], smx[1]), fmaxf(smx[2], smx[3]));
  mx = fmaxf(mx, 1e-8f);
  float scale = mx / 7.0f;                  // exact div to match jnp
#pragma unroll
  for (int i = 0; i < 4; i++) {
    float q = rintf(v[i] / scale);          // RNE == jnp.round
    q = fminf(fmaxf(q, -7.0f), 7.0f);
    d[t + 256 * i] = f2bf(q * scale);
  }
}

// ---------------- f32 -> bf16 ----------------------------------------------
__global__ void cvt_bf16(const float* __restrict__ src,
                         unsigned short* __restrict__ dst, int n) {
  int i = (blockIdx.x * 256 + threadIdx.x) * 4;
  if (i >= n) return;
  float4 f = *(const float4*)(src + i);
  ushort4 o;
  o.x = f2bf(f.x); o.y = f2bf(f.y); o.z = f2bf(f.z); o.w = f2bf(f.w);
  *(ushort4*)(dst + i) = o;
}

#define GLDS(g, l)                                                            \
  __builtin_amdgcn_global_load_lds((const __attribute__((address_space(1))) void*)(g), \
                                   (__attribute__((address_space(3))) void*)(l), 16, 0, 0)

// ---------------- GEMM: C[M,N] = A[M,K] * B[N,K]^T  (bf16 in, f32 out) -----
__global__ __launch_bounds__(256, 2) void gemm_bt(
    const unsigned short* __restrict__ A, const unsigned short* __restrict__ Bw,
    float* __restrict__ C, int N, int K, int nbn) {
  int bm = blockIdx.x / nbn, bn = blockIdx.x % nbn;
  int tid = threadIdx.x, w = tid >> 6, lane = tid & 63;
  int l15 = lane & 15, lh = lane >> 4;
  __shared__ __align__(16) unsigned short ldsA[2][128 * 64];
  __shared__ __align__(16) unsigned short ldsB[2][128 * 64];
  int wr = w >> 1, wc = w & 1;
  f32x4 zero = {0.f, 0.f, 0.f, 0.f};
  f32x4 acc[4][4];
#pragma unroll
  for (int i = 0; i < 4; i++)
#pragma unroll
    for (int j = 0; j < 4; j++) acc[i][j] = zero;

  int srow = lane >> 3, schunk = (lane & 7) ^ (lane >> 3);
  const unsigned short* gA0 = A  + (size_t)(bm * 128 + srow) * K + schunk * 8;
  const unsigned short* gB0 = Bw + (size_t)(bn * 128 + srow) * K + schunk * 8;

  int nk = K >> 6;
#pragma unroll
  for (int it = 0; it < 4; it++) {
    int seg = w * 4 + it;
    GLDS(gA0 + (size_t)(seg * 8) * K, (unsigned short*)ldsA[0] + seg * 512);
    GLDS(gB0 + (size_t)(seg * 8) * K, (unsigned short*)ldsB[0] + seg * 512);
  }
  __syncthreads();
  int cur = 0;
  for (int kt = 0; kt < nk; kt++) {
    if (kt + 1 < nk) {
      int k0 = (kt + 1) * 64;
#pragma unroll
      for (int it = 0; it < 4; it++) {
        int seg = w * 4 + it;
        GLDS(gA0 + (size_t)(seg * 8) * K + k0, (unsigned short*)ldsA[cur ^ 1] + seg * 512);
        GLDS(gB0 + (size_t)(seg * 8) * K + k0, (unsigned short*)ldsB[cur ^ 1] + seg * 512);
      }
    }
    const unsigned short* cA = ldsA[cur];
    const unsigned short* cB = ldsB[cur];
#pragma unroll
    for (int ks = 0; ks < 2; ks++) {
      bf16x8 af[4], bfr[4];
#pragma unroll
      for (int fm = 0; fm < 4; fm++) {
        int row = wr * 64 + fm * 16 + l15;
        int slot = (ks * 4 + lh) ^ (row & 7);
        af[fm] = *(const bf16x8*)(cA + row * 64 + slot * 8);
      }
#pragma unroll
      for (int fn = 0; fn < 4; fn++) {
        int row = wc * 64 + fn * 16 + l15;
        int slot = (ks * 4 + lh) ^ (row & 7);
        bfr[fn] = *(const bf16x8*)(cB + row * 64 + slot * 8);
      }
#pragma unroll
      for (int fm = 0; fm < 4; fm++)
#pragma unroll
        for (int fn = 0; fn < 4; fn++)
          acc[fm][fn] = __builtin_amdgcn_mfma_f32_16x16x32_bf16(af[fm], bfr[fn], acc[fm][fn], 0, 0, 0);
    }
    __syncthreads();
    cur ^= 1;
  }
#pragma unroll
  for (int fm = 0; fm < 4; fm++) {
    int r0 = bm * 128 + wr * 64 + fm * 16 + lh * 4;
#pragma unroll
    for (int fn = 0; fn < 4; fn++) {
      int c = bn * 128 + wc * 64 + fn * 16 + l15;
#pragma unroll
      for (int reg = 0; reg < 4; reg++)
        C[(size_t)(r0 + reg) * N + c] = acc[fm][fn][reg];
    }
  }
}

// ---------------- QKV GEMM with fused RMSNorm+RoPE+gain epilogue -----------
// M=4096 N=1536 K=1024, nbn=12.  Each wave's 64-col half == one head.
// hid = bn*2+wc: 0..15 q-heads, 16..19 k-heads, 20..23 v-heads.
__global__ __launch_bounds__(256, 2) void gemm_qkv(
    const unsigned short* __restrict__ A, const unsigned short* __restrict__ Bw,
    const float* __restrict__ gainp,
    unsigned short* __restrict__ qb, unsigned short* __restrict__ kbp,
    unsigned short* __restrict__ vbp) {
  const int K = 1024;
  int bm = blockIdx.x / 12, bn = blockIdx.x % 12;
  int tid = threadIdx.x, w = tid >> 6, lane = tid & 63;
  int l15 = lane & 15, lh = lane >> 4;
  __shared__ __align__(16) unsigned short ldsA[2][128 * 64];
  __shared__ __align__(16) unsigned short ldsB[2][128 * 64];
  int wr = w >> 1, wc = w & 1;
  f32x4 zero = {0.f, 0.f, 0.f, 0.f};
  f32x4 acc[4][4];
#pragma unroll
  for (int i = 0; i < 4; i++)
#pragma unroll
    for (int j = 0; j < 4; j++) acc[i][j] = zero;

  int srow = lane >> 3, schunk = (lane & 7) ^ (lane >> 3);
  const unsigned short* gA0 = A  + (size_t)(bm * 128 + srow) * K + schunk * 8;
  const unsigned short* gB0 = Bw + (size_t)(bn * 128 + srow) * K + schunk * 8;

#pragma unroll
  for (int it = 0; it < 4; it++) {
    int seg = w * 4 + it;
    GLDS(gA0 + (size_t)(seg * 8) * K, (unsigned short*)ldsA[0] + seg * 512);
    GLDS(gB0 + (size_t)(seg * 8) * K, (unsigned short*)ldsB[0] + seg * 512);
  }
  __syncthreads();
  int cur = 0;
  for (int kt = 0; kt < 16; kt++) {
    if (kt + 1 < 16) {
      int k0 = (kt + 1) * 64;
#pragma unroll
      for (int it = 0; it < 4; it++) {
        int seg = w * 4 + it;
        GLDS(gA0 + (size_t)(seg * 8) * K + k0, (unsigned short*)ldsA[cur ^ 1] + seg * 512);
        GLDS(gB0 + (size_t)(seg * 8) * K + k0, (unsigned short*)ldsB[cur ^ 1] + seg * 512);
      }
    }
    const unsigned short* cA = ldsA[cur];
    const unsigned short* cB = ldsB[cur];
#pragma unroll
    for (int ks = 0; ks < 2; ks++) {
      bf16x8 af[4], bfr[4];
#pragma unroll
      for (int fm = 0; fm < 4; fm++) {
        int row = wr * 64 + fm * 16 + l15;
        int slot = (ks * 4 + lh) ^ (row & 7);
        af[fm] = *(const bf16x8*)(cA + row * 64 + slot * 8);
      }
#pragma unroll
      for (int fn = 0; fn < 4; fn++) {
        int row = wc * 64 + fn * 16 + l15;
        int slot = (ks * 4 + lh) ^ (row & 7);
        bfr[fn] = *(const bf16x8*)(cB + row * 64 + slot * 8);
      }
#pragma unroll
      for (int fm = 0; fm < 4; fm++)
#pragma unroll
        for (int fn = 0; fn < 4; fn++)
          acc[fm][fn] = __builtin_amdgcn_mfma_f32_16x16x32_bf16(af[fm], bfr[fn], acc[fm][fn], 0, 0, 0);
    }
    __syncthreads();
    cur ^= 1;
  }

  // ---- fused epilogue ----
  int hid = bn * 2 + wc;
  int rbase = bm * 128 + wr * 64;
  if (hid >= 20) {
    int vh = hid - 20;
#pragma unroll
    for (int fm = 0; fm < 4; fm++)
#pragma unroll
      for (int reg = 0; reg < 4; reg++) {
        int r = rbase + fm * 16 + lh * 4 + reg;
        int b = r >> 11, s = r & 2047;
        unsigned short* dst = vbp + (((size_t)(b * 4 + vh) * 2048 + s) << 6);
#pragma unroll
        for (int fn = 0; fn < 4; fn++)
          dst[fn * 16 + l15] = f2bf(acc[fm][fn][reg]);
      }
  } else {
    bool isq = hid < 16;
    float gn = isq ? gainp[hid] : 1.0f;
    float invf0 = __expf(-0.28782313662425572f * (float)l15);         // ln(1e4)/32
    float invf1 = __expf(-0.28782313662425572f * (float)(l15 + 16));
#pragma unroll
    for (int fm = 0; fm < 4; fm++)
#pragma unroll
      for (int reg = 0; reg < 4; reg++) {
        float y0 = acc[fm][0][reg], y1 = acc[fm][1][reg];
        float y2 = acc[fm][2][reg], y3 = acc[fm][3][reg];
        float ss = y0 * y0 + y1 * y1 + y2 * y2 + y3 * y3;
        ss += __shfl_xor(ss, 1); ss += __shfl_xor(ss, 2);
        ss += __shfl_xor(ss, 4); ss += __shfl_xor(ss, 8);
        float rn = rsqrtf(ss * 0.015625f + 1.1920929e-7f);
        y0 *= rn; y1 *= rn; y2 *= rn; y3 *= rn;
        int r = rbase + fm * 16 + lh * 4 + reg;
        int b = r >> 11, s = r & 2047;
        float c0, s0n, c1, s1n;
        __sincosf((float)s * invf0, &s0n, &c0);
        __sincosf((float)s * invf1, &s1n, &c1);
        float o0 = (y0 * c0 + y2 * s0n) * gn;
        float o1 = (y1 * c1 + y3 * s1n) * gn;
        float o2 = (y2 * c0 - y0 * s0n) * gn;
        float o3 = (y3 * c1 - y1 * s1n) * gn;
        unsigned short* dst = isq
          ? qb  + (((size_t)(b * 16 + hid) * 2048 + s) << 6)
          : kbp + (((size_t)(b * 4 + (hid - 16)) * 2048 + s) << 6);
        dst[l15]      = f2bf(o0);
        dst[l15 + 16] = f2bf(o1);
        dst[l15 + 32] = f2bf(o2);
        dst[l15 + 48] = f2bf(o3);
      }
  }
}

// ---------------- V transpose + kv-permute (bf16 in, per-64 group) ---------
// Vp[d][g*64 + p] = V[g*64 + c64(p)][d],  c64(p) = ((p&3)<<4)|(p>>2).
__global__ void v_transpose(const unsigned short* __restrict__ vbp,
                            unsigned short* __restrict__ vt) {
  int bid = blockIdx.x;          // bk*32 + st
  int st = bid & 31, bk = bid >> 5;
  __shared__ unsigned short tile[64][72];
  int t = threadIdx.x;
  int sl = t >> 2, d0 = (t & 3) * 16;
  const unsigned short* src = vbp + (((size_t)bk * 2048 + st * 64 + sl) << 6) + d0;
  *(ushort4*)&tile[sl][d0]      = *(const ushort4*)(src);
  *(ushort4*)&tile[sl][d0 + 4]  = *(const ushort4*)(src + 4);
  *(ushort4*)&tile[sl][d0 + 8]  = *(const ushort4*)(src + 8);
  *(ushort4*)&tile[sl][d0 + 12] = *(const ushort4*)(src + 12);
  __syncthreads();
  int d = t >> 2, p0 = (t & 3) * 16;
  unsigned short* dst = vt + ((size_t)bk * 64 + d) * 2048 + st * 64 + p0;
#pragma unroll
  for (int jo = 0; jo < 16; jo += 4) {
    ushort4 a;
#pragma unroll
    for (int j = 0; j < 4; j++) {
      int p = p0 + jo + j;
      int c = ((p & 3) << 4) | (p >> 2);
      ((unsigned short*)&a)[j] = tile[c][d];
    }
    *(ushort4*)(dst + jo) = a;
  }
}

// ---------------- causal flash attention (4-wave, dbuf KV=64) --------------
#define PSTR 72

template<bool MASK>
__device__ __forceinline__ void attn_tile(
    int kv0, int q0, int l15, int lh, float M2,
    const unsigned short* ldsK, const unsigned short* ldsV, unsigned short* pw,
    const bf16x8 (&qf)[2][2], float (&lsum)[2][4], f32x4 (&o)[2][4]) {
  const float K2 = 0.18033688011112042f;  // 0.125 * log2(e)
  f32x4 zero = {0.f, 0.f, 0.f, 0.f};
  f32x4 sc[2][4];
#pragma unroll
  for (int fm = 0; fm < 2; fm++)
#pragma unroll
    for (int fn = 0; fn < 4; fn++) sc[fm][fn] = zero;
#pragma unroll
  for (int ks = 0; ks < 2; ks++) {
    bf16x8 kf[4];
#pragma unroll
    for (int fn = 0; fn < 4; fn++) {
      int row = fn * 16 + l15;
      int slot = (ks * 4 + lh) ^ (row & 7);
      kf[fn] = *(const bf16x8*)(ldsK + row * 64 + slot * 8);
    }
#pragma unroll
    for (int fm = 0; fm < 2; fm++)
#pragma unroll
      for (int fn = 0; fn < 4; fn++)
        sc[fm][fn] = __builtin_amdgcn_mfma_f32_16x16x32_bf16(qf[fm][ks], kf[fn], sc[fm][fn], 0, 0, 0);
  }
#pragma unroll
  for (int fm = 0; fm < 2; fm++)
#pragma unroll
    for (int r = 0; r < 4; r++) {
      bf16x4 pk;
      float ls = 0.f;
#pragma unroll
      for (int fn = 0; fn < 4; fn++) {
        float s = __builtin_fmaf(sc[fm][fn][r], K2, -M2);
        if (MASK) {
          int col = kv0 + fn * 16 + l15;
          int row = q0 + fm * 16 + lh * 4 + r;
          if (col > row) s = -1e30f;
        }
        float p = __builtin_amdgcn_exp2f(s);
        ls += p;
        pk[fn] = (__bf16)p;
      }
      *(bf16x4*)(pw + (fm * 16 + lh * 4 + r) * PSTR + l15 * 4) = pk;
      lsum[fm][r] += ls;
    }
  asm volatile("s_waitcnt lgkmcnt(0)" ::: "memory");
  __builtin_amdgcn_sched_barrier(0);
#pragma unroll
  for (int ks2 = 0; ks2 < 2; ks2++) {
    bf16x8 vf[4], pf[2];
#pragma unroll
    for (int fn = 0; fn < 4; fn++) {
      int row = fn * 16 + l15;
      int slot = (ks2 * 4 + lh) ^ (row & 7);
      vf[fn] = *(const bf16x8*)(ldsV + row * 64 + slot * 8);
    }
#pragma unroll
    for (int fm = 0; fm < 2; fm++)
      pf[fm] = *(const bf16x8*)(pw + (fm * 16 + l15) * PSTR + ks2 * 32 + lh * 8);
#pragma unroll
    for (int fm = 0; fm < 2; fm++)
#pragma unroll
      for (int fn = 0; fn < 4; fn++)
        o[fm][fn] = __builtin_amdgcn_mfma_f32_16x16x32_bf16(pf[fm], vf[fn], o[fm][fn], 0, 0, 0);
  }
}

__global__ __launch_bounds__(256, 3) void attn_fwd(
    const unsigned short* __restrict__ qbuf, const unsigned short* __restrict__ kb,
    const unsigned short* __restrict__ vtb, const float* __restrict__ gain,
    unsigned short* __restrict__ ob) {
  int bid = blockIdx.x;
  int g = bid >> 5;
  int qblk = (g < 8) ? (15 - g) : (g - 8);   // pair heavy+light per CU
  int bh = bid & 31;
  int b = bh >> 4, h = bh & 15;
  int tid = threadIdx.x;
  int w = tid >> 6, lane = tid & 63;
  int l15 = lane & 15, lh = lane >> 4;
  int q0 = qblk * 128 + w * 32;
  int kvh = h >> 2;
  const unsigned short* Q  = qbuf + (size_t)(b * 16 + h) * (2048 * 64);
  const unsigned short* Kg = kb   + (size_t)(b * 4 + kvh) * (2048 * 64);
  const unsigned short* Vg = vtb  + (size_t)(b * 4 + kvh) * (64 * 2048);

  __shared__ __align__(16) unsigned short ldsK[2][64 * 64];
  __shared__ __align__(16) unsigned short ldsV[2][64 * 64];
  __shared__ __align__(16) unsigned short plds[4][32 * PSTR];
  unsigned short* pw = plds[w];

  float gn = gain[h];
  float M2 = __builtin_fmaf(fabsf(gn), 1.46f, 0.02f);  // static max bound

  bf16x8 qf[2][2];
#pragma unroll
  for (int fm = 0; fm < 2; fm++)
#pragma unroll
    for (int ks = 0; ks < 2; ks++)
      qf[fm][ks] = *(const bf16x8*)(Q + (q0 + fm * 16 + l15) * 64 + ks * 32 + lh * 8);

  f32x4 zero = {0.f, 0.f, 0.f, 0.f};
  f32x4 o[2][4];
  float lsum[2][4];
#pragma unroll
  for (int fm = 0; fm < 2; fm++)
#pragma unroll
    for (int r = 0; r < 4; r++) { lsum[fm][r] = 0.f; o[fm][r] = zero; }

  int srow = lane >> 3;
  int schunk = (lane & 7) ^ (lane >> 3);
  int full = q0 >> 6;
  int nt = 2 * qblk + 2;

#pragma unroll
  for (int it = 0; it < 2; it++) {
    int seg = w * 2 + it;
    GLDS(Kg + (size_t)(seg * 8 + srow) * 64 + schunk * 8,
         (unsigned short*)ldsK[0] + seg * 512);
    GLDS(Vg + (size_t)(seg * 8 + srow) * 2048 + schunk * 8,
         (unsigned short*)ldsV[0] + seg * 512);
  }
  __syncthreads();
  int cur = 0;
  for (int t = 0; t < nt; t++) {
    int kv0 = t * 64;
    if (t + 1 < nt) {
      int kn = kv0 + 64;
#pragma unroll
      for (int it = 0; it < 2; it++) {
        int seg = w * 2 + it;
        GLDS(Kg + (size_t)(kn + seg * 8 + srow) * 64 + schunk * 8,
             (unsigned short*)ldsK[cur ^ 1] + seg * 512);
        GLDS(Vg + (size_t)(seg * 8 + srow) * 2048 + kn + schunk * 8,
             (unsigned short*)ldsV[cur ^ 1] + seg * 512);
      }
    }
    if (t < full)
      attn_tile<false>(kv0, q0, l15, lh, M2, ldsK[cur], ldsV[cur], pw, qf, lsum, o);
    else if (kv0 <= q0 + 31)
      attn_tile<true>(kv0, q0, l15, lh, M2, ldsK[cur], ldsV[cur], pw, qf, lsum, o);
    __syncthreads();
    cur ^= 1;
  }

#pragma unroll
  for (int fm = 0; fm < 2; fm++)
#pragma unroll
    for (int r = 0; r < 4; r++) {
      float l = lsum[fm][r];
      l += __shfl_xor(l, 1);
      l += __shfl_xor(l, 2);
      l += __shfl_xor(l, 4);
      l += __shfl_xor(l, 8);
      float inv = 1.0f / l;
      int row = q0 + fm * 16 + lh * 4 + r;
#pragma unroll
      for (int fn = 0; fn < 4; fn++) {
        int c = fn * 16 + l15;
        ob[(size_t)(b * 2048 + row) * 1024 + h * 64 + c] = f2bf(o[fm][fn][r] * inv);
      }
    }
}

// ---------------------------------------------------------------------------
extern "C" void kernel_launch(void* const* d_in, const int* in_sizes, int n_in,
                              void* d_out, int out_size, void* d_ws, size_t ws_size,
                              hipStream_t stream) {
  const float* x    = (const float*)d_in[0];
  const float* w_q  = (const float*)d_in[1];
  const float* w_k  = (const float*)d_in[2];
  const float* w_v  = (const float*)d_in[3];
  const float* w_p  = (const float*)d_in[4];
  const float* gain = (const float*)d_in[5];
  float* out = (float*)d_out;

  char* ws = (char*)d_ws;
  unsigned short* x_bf  = (unsigned short*)ws;                   //  8 MB
  unsigned short* wqkv  = (unsigned short*)(ws + (8u << 20));    //  3 MB
  unsigned short* wp    = (unsigned short*)(ws + (11u << 20));   //  2 MB
  unsigned short* qbuf  = (unsigned short*)(ws + (13u << 20));   //  8 MB
  unsigned short* kbuf  = (unsigned short*)(ws + (21u << 20));   //  2 MB
  unsigned short* vbuf  = (unsigned short*)(ws + (23u << 20));   //  2 MB
  unsigned short* vtbuf = (unsigned short*)(ws + (25u << 20));   //  2 MB
  unsigned short* aout  = (unsigned short*)(ws + (27u << 20));   //  8 MB

  quant_rows<<<1024, 256, 0, stream>>>(w_q, wqkv, 1024);
  quant_rows<<<256, 256, 0, stream>>>(w_k, wqkv + 1024 * 1024, 1024);
  quant_rows<<<256, 256, 0, stream>>>(w_v, wqkv + 1280 * 1024, 1024);
  quant_rows<<<1024, 256, 0, stream>>>(w_p, wp, 1024);
  cvt_bf16<<<4096, 256, 0, stream>>>(x, x_bf, 4194304);
  gemm_qkv<<<32 * 12, 256, 0, stream>>>(x_bf, wqkv, gain, qbuf, kbuf, vbuf);
  v_transpose<<<256, 256, 0, stream>>>(vbuf, vtbuf);
  attn_fwd<<<512, 256, 0, stream>>>(qbuf, kbuf, vtbuf, gain, aout);
  gemm_bt<<<32 * 8, 256, 0, stream>>>(aout, wp, out, 1024, 1024, 8);
}